// Round 1
// baseline (1967.867 us; speedup 1.0000x reference)
//
#include <hip/hip_runtime.h>
#include <math.h>

#define N_ROWS 4096
#define E_DIM  512
#define C_CLS  50257
#define NCT    786          // ceil(50257 / 64)
#define COS_M  (-0.6536436208636119f)   // cos(4.0)
#define SIN_M  (-0.7568024953079282f)   // sin(4.0)
#define EPSN   1e-12f

typedef __bf16 bf16x8 __attribute__((ext_vector_type(8)));
typedef float  f32x4  __attribute__((ext_vector_type(4)));

__device__ inline unsigned short f2bf(float f) {
  unsigned int u = __float_as_uint(f);
  u += 0x7FFFu + ((u >> 16) & 1u);     // round-to-nearest-even
  return (unsigned short)(u >> 16);
}

// Row L2-normalize: src [rows,512] f32 -> dst bf16, norms f32. 1 block/row, 256 thr.
__global__ __launch_bounds__(256) void k_norm(const float* __restrict__ src,
                                              unsigned short* __restrict__ dst,
                                              float* __restrict__ norms) {
  int row = blockIdx.x;
  int tid = threadIdx.x;
  const float2* p = (const float2*)(src + (size_t)row * E_DIM);
  float2 v = p[tid];
  float ss = v.x * v.x + v.y * v.y;
  #pragma unroll
  for (int off = 32; off > 0; off >>= 1) ss += __shfl_down(ss, off, 64);
  __shared__ float sb[4];
  if ((tid & 63) == 0) sb[tid >> 6] = ss;
  __syncthreads();
  float tot = sb[0] + sb[1] + sb[2] + sb[3];
  float nrm = sqrtf(tot);
  if (tid == 0) norms[row] = nrm;
  float inv = 1.0f / fmaxf(nrm, EPSN);
  ushort2 o;
  o.x = f2bf(v.x * inv);
  o.y = f2bf(v.y * inv);
  ((ushort2*)(dst + (size_t)row * E_DIM))[tid] = o;
}

// Precise fp32 target cosine per row. 1 block/row, 256 thr.
__global__ __launch_bounds__(256) void k_target(const float* __restrict__ x,
                                                const float* __restrict__ w,
                                                const int* __restrict__ label,
                                                const float* __restrict__ xn,
                                                const float* __restrict__ wn,
                                                float* __restrict__ t) {
  int row = blockIdx.x;
  int lab = label[row];
  int tid = threadIdx.x;
  const float2* px = (const float2*)(x + (size_t)row * E_DIM);
  const float2* pw = (const float2*)(w + (size_t)lab * E_DIM);
  float2 a = px[tid], b = pw[tid];
  float s = a.x * b.x + a.y * b.y;
  #pragma unroll
  for (int off = 32; off > 0; off >>= 1) s += __shfl_down(s, off, 64);
  __shared__ float sb[4];
  if ((tid & 63) == 0) sb[tid >> 6] = s;
  __syncthreads();
  if (tid == 0) {
    float tot = sb[0] + sb[1] + sb[2] + sb[3];
    t[row] = tot / (fmaxf(xn[row], EPSN) * fmaxf(wn[lab], EPSN));
  }
}

// Fused GEMM (cos = nx . nw^T) + per-tile online (max, sumexp).
// grid = (NCT, N_ROWS/64), block = 256 (4 waves). Block tile 64 rows x 64 cls.
// Wave w handles rows [rtile*64 + w*16, +16), 4 col-subtiles of 16.
__global__ __launch_bounds__(256) void k_gemm(const unsigned short* __restrict__ nx,
                                              const unsigned short* __restrict__ nw,
                                              const int* __restrict__ label,
                                              float* __restrict__ pm,
                                              float* __restrict__ pl,
                                              float* __restrict__ tbf) {
  int ctile = blockIdx.x;
  int rtile = blockIdx.y;
  int wave = threadIdx.x >> 6;
  int lane = threadIdx.x & 63;
  int q = lane >> 4;        // quad 0..3
  int l15 = lane & 15;
  int rowBase = rtile * 64 + wave * 16;
  int colBase = ctile * 64;

  f32x4 acc[4] = {};
  const unsigned short* aPtr = nx + (size_t)(rowBase + l15) * E_DIM + q * 8;
  const unsigned short* bPtr[4];
  #pragma unroll
  for (int s = 0; s < 4; s++) {
    int c = colBase + s * 16 + l15;
    if (c >= C_CLS) c = C_CLS - 1;      // clamp; masked in epilogue
    bPtr[s] = nw + (size_t)c * E_DIM + q * 8;
  }

  #pragma unroll 4
  for (int k = 0; k < E_DIM; k += 32) {
    bf16x8 af = *(const bf16x8*)(aPtr + k);
    #pragma unroll
    for (int s = 0; s < 4; s++) {
      bf16x8 bf = *(const bf16x8*)(bPtr[s] + k);
      acc[s] = __builtin_amdgcn_mfma_f32_16x16x32_bf16(af, bf, acc[s], 0, 0, 0);
    }
  }

  // Epilogue: C/D layout row = rowBase + 4*q + reg, col = colBase + s*16 + l15.
  // The 16 lanes with the same q hold one row's 64 columns.
  #pragma unroll
  for (int reg = 0; reg < 4; reg++) {
    int grow = rowBase + 4 * q + reg;
    int lab = label[grow];
    float v[4];
    float vmax = -INFINITY;
    #pragma unroll
    for (int s = 0; s < 4; s++) {
      int col = colBase + s * 16 + l15;
      v[s] = acc[s][reg];
      if (col < C_CLS) {
        vmax = fmaxf(vmax, v[s]);
        if (col == lab) tbf[grow] = v[s];   // record bf16-GEMM cos at label
      }
    }
    #pragma unroll
    for (int m = 1; m < 16; m <<= 1) vmax = fmaxf(vmax, __shfl_xor(vmax, m, 64));
    float sum = 0.f;
    #pragma unroll
    for (int s = 0; s < 4; s++) {
      int col = colBase + s * 16 + l15;
      if (col < C_CLS) sum += __expf(v[s] - vmax);
    }
    #pragma unroll
    for (int m = 1; m < 16; m <<= 1) sum += __shfl_xor(sum, m, 64);
    if (l15 == 0) {
      pm[(size_t)grow * NCT + ctile] = vmax;
      pl[(size_t)grow * NCT + ctile] = sum;
    }
  }
}

// Combine per-tile partials -> row logsumexp, swap in margin logit, mean-reduce.
__global__ __launch_bounds__(256) void k_reduce(const float* __restrict__ pm,
                                                const float* __restrict__ pl,
                                                const float* __restrict__ t,
                                                const float* __restrict__ tbf,
                                                float* __restrict__ out) {
  int row = blockIdx.x;
  int tid = threadIdx.x;
  float m = -INFINITY, l = 0.f;
  for (int j = tid; j < NCT; j += 256) {
    float mj = pm[(size_t)row * NCT + j];
    float lj = pl[(size_t)row * NCT + j];
    if (mj > m) { l = l * __expf(m - mj) + lj; m = mj; }
    else        { l += lj * __expf(mj - m); }
  }
  __shared__ float sm[256], sl[256];
  sm[tid] = m; sl[tid] = l;
  __syncthreads();
  for (int s = 128; s > 0; s >>= 1) {
    if (tid < s) {
      float m1 = sm[tid], l1 = sl[tid];
      float m2 = sm[tid + s], l2 = sl[tid + s];
      float M = fmaxf(m1, m2);
      float L;
      if (M == -INFINITY) L = 0.f;
      else L = l1 * __expf(m1 - M) + l2 * __expf(m2 - M);
      sm[tid] = M; sl[tid] = L;
    }
    __syncthreads();
  }
  if (tid == 0) {
    float M0 = sm[0], L0 = sl[0];
    float tv = t[row];
    float tb = tbf[row];
    float sint = sqrtf(fmaxf(0.f, 1.f - tv * tv));
    float cosm = tv * COS_M - sint * SIN_M;
    float M = fmaxf(M0, cosm);
    float L = L0 * expf(M0 - M) - expf(tb - M) + expf(cosm - M);
    float loss = logf(L) + M - cosm;
    atomicAdd(out, loss * (1.0f / N_ROWS));
  }
}

extern "C" void kernel_launch(void* const* d_in, const int* in_sizes, int n_in,
                              void* d_out, int out_size, void* d_ws, size_t ws_size,
                              hipStream_t stream) {
  const float* x = (const float*)d_in[0];
  const int* label = (const int*)d_in[1];
  const float* w = (const float*)d_in[2];
  float* out = (float*)d_out;
  char* ws = (char*)d_ws;

  size_t off = 0;
  unsigned short* nx = (unsigned short*)(ws + off); off += (size_t)N_ROWS * E_DIM * 2;   // 4 MB
  unsigned short* nw = (unsigned short*)(ws + off); off += (size_t)C_CLS * E_DIM * 2;    // 51.5 MB
  float* xn  = (float*)(ws + off); off += (size_t)N_ROWS * 4;
  float* wn  = (float*)(ws + off); off += (size_t)50304 * 4;
  float* tv  = (float*)(ws + off); off += (size_t)N_ROWS * 4;
  float* tbf = (float*)(ws + off); off += (size_t)N_ROWS * 4;
  float* pm  = (float*)(ws + off); off += (size_t)N_ROWS * NCT * 4;                      // 12.9 MB
  float* pl  = (float*)(ws + off); off += (size_t)N_ROWS * NCT * 4;                      // 12.9 MB

  hipMemsetAsync(d_out, 0, sizeof(float), stream);
  k_norm<<<N_ROWS, 256, 0, stream>>>(x, nx, xn);
  k_norm<<<C_CLS, 256, 0, stream>>>(w, nw, wn);
  k_target<<<N_ROWS, 256, 0, stream>>>(x, w, label, xn, wn, tv);
  dim3 g(NCT, N_ROWS / 64);
  k_gemm<<<g, 256, 0, stream>>>(nx, nw, label, pm, pl, tbf);
  k_reduce<<<N_ROWS, 256, 0, stream>>>(pm, pl, tv, tbf, out);
}

// Round 2
// 896.363 us; speedup vs baseline: 2.1954x; 2.1954x over previous
//
#include <hip/hip_runtime.h>
#include <math.h>

#define N_ROWS 4096
#define E_DIM  512
#define C_CLS  50257
#define NCT2   786          // partials per row: 393 col-tiles * 2 wave-halves
#define NTILE  393          // ceil(50257/128)
#define COS_M  (-0.6536436208636119f)   // cos(4.0)
#define SIN_M  (-0.7568024953079282f)   // sin(4.0)
#define EPSN   1e-12f

typedef __bf16 bf16x8 __attribute__((ext_vector_type(8)));
typedef float  f32x4  __attribute__((ext_vector_type(4)));

__device__ inline unsigned short f2bf(float f) {
  unsigned int u = __float_as_uint(f);
  u += 0x7FFFu + ((u >> 16) & 1u);     // round-to-nearest-even
  return (unsigned short)(u >> 16);
}

// Row L2-normalize: src [rows,512] f32 -> dst bf16, norms f32. 1 block/row, 256 thr.
__global__ __launch_bounds__(256) void k_norm(const float* __restrict__ src,
                                              unsigned short* __restrict__ dst,
                                              float* __restrict__ norms) {
  int row = blockIdx.x;
  int tid = threadIdx.x;
  const float2* p = (const float2*)(src + (size_t)row * E_DIM);
  float2 v = p[tid];
  float ss = v.x * v.x + v.y * v.y;
  #pragma unroll
  for (int off = 32; off > 0; off >>= 1) ss += __shfl_down(ss, off, 64);
  __shared__ float sb[4];
  if ((tid & 63) == 0) sb[tid >> 6] = ss;
  __syncthreads();
  float tot = sb[0] + sb[1] + sb[2] + sb[3];
  float nrm = sqrtf(tot);
  if (tid == 0) norms[row] = nrm;
  float inv = 1.0f / fmaxf(nrm, EPSN);
  ushort2 o;
  o.x = f2bf(v.x * inv);
  o.y = f2bf(v.y * inv);
  ((ushort2*)(dst + (size_t)row * E_DIM))[tid] = o;
}

// Precise fp32 target cosine per row. 1 block/row, 256 thr.
__global__ __launch_bounds__(256) void k_target(const float* __restrict__ x,
                                                const float* __restrict__ w,
                                                const int* __restrict__ label,
                                                const float* __restrict__ xn,
                                                const float* __restrict__ wn,
                                                float* __restrict__ t) {
  int row = blockIdx.x;
  int lab = label[row];
  int tid = threadIdx.x;
  const float2* px = (const float2*)(x + (size_t)row * E_DIM);
  const float2* pw = (const float2*)(w + (size_t)lab * E_DIM);
  float2 a = px[tid], b = pw[tid];
  float s = a.x * b.x + a.y * b.y;
  #pragma unroll
  for (int off = 32; off > 0; off >>= 1) s += __shfl_down(s, off, 64);
  __shared__ float sb[4];
  if ((tid & 63) == 0) sb[tid >> 6] = s;
  __syncthreads();
  if (tid == 0) {
    float tot = sb[0] + sb[1] + sb[2] + sb[3];
    t[row] = tot / (fmaxf(xn[row], EPSN) * fmaxf(wn[lab], EPSN));
  }
}

// Fused 128x128-tile GEMM (cos = nx . nw^T) + per-row-tile online (max, sumexp).
// grid = (NTILE, 32), block = 256 (4 waves, 2x2). BK=64, K=512 -> 8 iters.
// LDS layout = MFMA fragment order: chunk c (= grp16*2 + ks) holds the 64-lane
// fragment block {A[grp16*16 + l15][ks*32 + q*8 .. +7]}, 1024 B contiguous.
// Staging via global_load_lds (wave-uniform LDS base + lane*16) matches exactly;
// fragment ds_read_b128 is a contiguous 1024 B wave read -> no bank conflicts.
__global__ __launch_bounds__(256) void k_gemm(const unsigned short* __restrict__ nx,
                                              const unsigned short* __restrict__ nw,
                                              const int* __restrict__ label,
                                              float* __restrict__ pm,
                                              float* __restrict__ pl,
                                              float* __restrict__ tbf) {
  __shared__ bf16x8 lds_a[16 * 64];   // 16 KB
  __shared__ bf16x8 lds_b[16 * 64];   // 16 KB

  int ctile = blockIdx.x;
  int rtile = blockIdx.y;
  int tid = threadIdx.x;
  int wave = tid >> 6;
  int lane = tid & 63;
  int q = lane >> 4;
  int l15 = lane & 15;
  int wr = wave >> 1;      // row half (0/1)
  int wc = wave & 1;       // col half (0/1)
  int rowTile = rtile * 128;
  int colTile = ctile * 128;

  // Per-lane global source pointers for the 4 A-chunks and 4 B-chunks this
  // wave stages each K-iter. Chunk id c = wave*4 + t; grp16 = c>>1, ks = c&1.
  const unsigned short* gA[4];
  const unsigned short* gB[4];
  #pragma unroll
  for (int t = 0; t < 4; t++) {
    int c = wave * 4 + t;
    int g16 = c >> 1, ks = c & 1;
    gA[t] = nx + (size_t)(rowTile + g16 * 16 + l15) * E_DIM + ks * 32 + q * 8;
    int cls = colTile + g16 * 16 + l15;
    if (cls >= C_CLS) cls = C_CLS - 1;          // clamp; masked in epilogue
    gB[t] = nw + (size_t)cls * E_DIM + ks * 32 + q * 8;
  }

  f32x4 acc[4][4] = {};

  for (int kt = 0; kt < 8; kt++) {
    __syncthreads();   // previous iter's LDS reads done
    #pragma unroll
    for (int t = 0; t < 4; t++) {
      int c = wave * 4 + t;
      __builtin_amdgcn_global_load_lds(
          (const __attribute__((address_space(1))) void*)(gA[t] + kt * 64),
          (__attribute__((address_space(3))) void*)(&lds_a[c * 64]), 16, 0, 0);
      __builtin_amdgcn_global_load_lds(
          (const __attribute__((address_space(1))) void*)(gB[t] + kt * 64),
          (__attribute__((address_space(3))) void*)(&lds_b[c * 64]), 16, 0, 0);
    }
    __syncthreads();   // staging complete (compiler drains vmcnt before barrier)

    #pragma unroll
    for (int ks = 0; ks < 2; ks++) {
      bf16x8 afr[4], bfr[4];
      #pragma unroll
      for (int i = 0; i < 4; i++)
        afr[i] = lds_a[((wr * 4 + i) * 2 + ks) * 64 + lane];
      #pragma unroll
      for (int j = 0; j < 4; j++)
        bfr[j] = lds_b[((wc * 4 + j) * 2 + ks) * 64 + lane];
      #pragma unroll
      for (int i = 0; i < 4; i++)
        #pragma unroll
        for (int j = 0; j < 4; j++)
          acc[i][j] = __builtin_amdgcn_mfma_f32_16x16x32_bf16(afr[i], bfr[j],
                                                              acc[i][j], 0, 0, 0);
    }
  }

  // Epilogue. C/D layout: within a 16x16 tile, row = 4*q + reg, col = l15.
  // Wave covers rows [rowTile + wr*64, +64), cols [colTile + wc*64, +64).
  int colW = colTile + wc * 64;
  #pragma unroll
  for (int msub = 0; msub < 4; msub++) {
    #pragma unroll
    for (int reg = 0; reg < 4; reg++) {
      int grow = rowTile + wr * 64 + msub * 16 + 4 * q + reg;
      int lab = label[grow];
      float v[4];
      float vmax = -INFINITY;
      #pragma unroll
      for (int ns = 0; ns < 4; ns++) {
        int col = colW + ns * 16 + l15;
        v[ns] = acc[msub][ns][reg];
        if (col < C_CLS) {
          vmax = fmaxf(vmax, v[ns]);
          if (col == lab) tbf[grow] = v[ns];   // bf16-GEMM cos at label position
        }
      }
      #pragma unroll
      for (int m = 1; m < 16; m <<= 1) vmax = fmaxf(vmax, __shfl_xor(vmax, m, 64));
      float sum = 0.f;
      #pragma unroll
      for (int ns = 0; ns < 4; ns++) {
        int col = colW + ns * 16 + l15;
        if (col < C_CLS) sum += __expf(v[ns] - vmax);
      }
      #pragma unroll
      for (int m = 1; m < 16; m <<= 1) sum += __shfl_xor(sum, m, 64);
      if (l15 == 0) {
        size_t p = (size_t)grow * NCT2 + (size_t)ctile * 2 + wc;
        pm[p] = vmax;
        pl[p] = sum;
      }
    }
  }
}

// Combine per-tile partials -> row logsumexp, swap in margin logit, mean-reduce.
__global__ __launch_bounds__(256) void k_reduce(const float* __restrict__ pm,
                                                const float* __restrict__ pl,
                                                const float* __restrict__ t,
                                                const float* __restrict__ tbf,
                                                float* __restrict__ out) {
  int row = blockIdx.x;
  int tid = threadIdx.x;
  float m = -INFINITY, l = 0.f;
  for (int j = tid; j < NCT2; j += 256) {
    float mj = pm[(size_t)row * NCT2 + j];
    float lj = pl[(size_t)row * NCT2 + j];
    if (mj > m) { l = l * __expf(m - mj) + lj; m = mj; }
    else        { l += lj * __expf(mj - m); }
  }
  __shared__ float sm[256], sl[256];
  sm[tid] = m; sl[tid] = l;
  __syncthreads();
  for (int s = 128; s > 0; s >>= 1) {
    if (tid < s) {
      float m1 = sm[tid], l1 = sl[tid];
      float m2 = sm[tid + s], l2 = sl[tid + s];
      float M = fmaxf(m1, m2);
      float L;
      if (M == -INFINITY) L = 0.f;
      else L = l1 * __expf(m1 - M) + l2 * __expf(m2 - M);
      sm[tid] = M; sl[tid] = L;
    }
    __syncthreads();
  }
  if (tid == 0) {
    float M0 = sm[0], L0 = sl[0];
    float tv = t[row];
    float tb = tbf[row];
    float sint = sqrtf(fmaxf(0.f, 1.f - tv * tv));
    float cosm = tv * COS_M - sint * SIN_M;
    float M = fmaxf(M0, cosm);
    float L = L0 * expf(M0 - M) - expf(tb - M) + expf(cosm - M);
    float loss = logf(L) + M - cosm;
    atomicAdd(out, loss * (1.0f / N_ROWS));
  }
}

extern "C" void kernel_launch(void* const* d_in, const int* in_sizes, int n_in,
                              void* d_out, int out_size, void* d_ws, size_t ws_size,
                              hipStream_t stream) {
  const float* x = (const float*)d_in[0];
  const int* label = (const int*)d_in[1];
  const float* w = (const float*)d_in[2];
  float* out = (float*)d_out;
  char* ws = (char*)d_ws;

  size_t off = 0;
  unsigned short* nx = (unsigned short*)(ws + off); off += (size_t)N_ROWS * E_DIM * 2;   // 4 MB
  unsigned short* nw = (unsigned short*)(ws + off); off += (size_t)C_CLS * E_DIM * 2;    // 51.5 MB
  float* xn  = (float*)(ws + off); off += (size_t)N_ROWS * 4;
  float* wn  = (float*)(ws + off); off += (size_t)50304 * 4;
  float* tv  = (float*)(ws + off); off += (size_t)N_ROWS * 4;
  float* tbf = (float*)(ws + off); off += (size_t)N_ROWS * 4;
  float* pm  = (float*)(ws + off); off += (size_t)N_ROWS * NCT2 * 4;                     // 12.9 MB
  float* pl  = (float*)(ws + off); off += (size_t)N_ROWS * NCT2 * 4;                     // 12.9 MB

  hipMemsetAsync(d_out, 0, sizeof(float), stream);
  k_norm<<<N_ROWS, 256, 0, stream>>>(x, nx, xn);
  k_norm<<<C_CLS, 256, 0, stream>>>(w, nw, wn);
  k_target<<<N_ROWS, 256, 0, stream>>>(x, w, label, xn, wn, tv);
  dim3 g(NTILE, N_ROWS / 128);
  k_gemm<<<g, 256, 0, stream>>>(nx, nw, label, pm, pl, tbf);
  k_reduce<<<N_ROWS, 256, 0, stream>>>(pm, pl, tv, tbf, out);
}

// Round 3
// 750.616 us; speedup vs baseline: 2.6217x; 1.1942x over previous
//
#include <hip/hip_runtime.h>
#include <math.h>

#define N_ROWS 4096
#define E_DIM  512
#define C_CLS  50257
#define NCT2   786          // partials per row: 393 col-tiles * 2 wave-halves
#define NTILE  393          // ceil(50257/128)
#define COS_M  (-0.6536436208636119f)   // cos(4.0)
#define SIN_M  (-0.7568024953079282f)   // sin(4.0)
#define EPSN   1e-12f

typedef __bf16 bf16x8 __attribute__((ext_vector_type(8)));
typedef float  f32x4  __attribute__((ext_vector_type(4)));

__device__ inline unsigned short f2bf(float f) {
  unsigned int u = __float_as_uint(f);
  u += 0x7FFFu + ((u >> 16) & 1u);     // round-to-nearest-even
  return (unsigned short)(u >> 16);
}

// Row L2-normalize: src [rows,512] f32 -> dst bf16, norms f32. 1 block/row, 256 thr.
__global__ __launch_bounds__(256) void k_norm(const float* __restrict__ src,
                                              unsigned short* __restrict__ dst,
                                              float* __restrict__ norms) {
  int row = blockIdx.x;
  int tid = threadIdx.x;
  const float2* p = (const float2*)(src + (size_t)row * E_DIM);
  float2 v = p[tid];
  float ss = v.x * v.x + v.y * v.y;
  #pragma unroll
  for (int off = 32; off > 0; off >>= 1) ss += __shfl_down(ss, off, 64);
  __shared__ float sb[4];
  if ((tid & 63) == 0) sb[tid >> 6] = ss;
  __syncthreads();
  float tot = sb[0] + sb[1] + sb[2] + sb[3];
  float nrm = sqrtf(tot);
  if (tid == 0) norms[row] = nrm;
  float inv = 1.0f / fmaxf(nrm, EPSN);
  ushort2 o;
  o.x = f2bf(v.x * inv);
  o.y = f2bf(v.y * inv);
  ((ushort2*)(dst + (size_t)row * E_DIM))[tid] = o;
}

// Precise fp32 target cosine per row. 1 block/row, 256 thr.
__global__ __launch_bounds__(256) void k_target(const float* __restrict__ x,
                                                const float* __restrict__ w,
                                                const int* __restrict__ label,
                                                const float* __restrict__ xn,
                                                const float* __restrict__ wn,
                                                float* __restrict__ t) {
  int row = blockIdx.x;
  int lab = label[row];
  int tid = threadIdx.x;
  const float2* px = (const float2*)(x + (size_t)row * E_DIM);
  const float2* pw = (const float2*)(w + (size_t)lab * E_DIM);
  float2 a = px[tid], b = pw[tid];
  float s = a.x * b.x + a.y * b.y;
  #pragma unroll
  for (int off = 32; off > 0; off >>= 1) s += __shfl_down(s, off, 64);
  __shared__ float sb[4];
  if ((tid & 63) == 0) sb[tid >> 6] = s;
  __syncthreads();
  if (tid == 0) {
    float tot = sb[0] + sb[1] + sb[2] + sb[3];
    t[row] = tot / (fmaxf(xn[row], EPSN) * fmaxf(wn[lab], EPSN));
  }
}

// Fused 128x128-tile GEMM (cos = nx . nw^T) + per-row-tile online (max, sumexp).
// grid = (32, NTILE): rtile varies FASTEST so all 32 rtiles of a given ctile
// run near-simultaneously -> each B tile is fetched once and reused 32x via
// L2/L3 (co-resident B footprint ~3 MB/XCD-L2). block = 256 (4 waves, 2x2).
// BK=64, K=512 -> 8 iters, register-prefetch pipeline:
//   barrier(stage k visible) -> ds_read frags k -> barrier(LDS free) ->
//   issue global_load_lds k+1 -> MFMA k   (load latency hides under MFMA).
// LDS layout = MFMA fragment order (chunk = 64 lanes x 16 B, contiguous).
__global__ __launch_bounds__(256) void k_gemm(const unsigned short* __restrict__ nx,
                                              const unsigned short* __restrict__ nw,
                                              const int* __restrict__ label,
                                              float* __restrict__ pm,
                                              float* __restrict__ pl,
                                              float* __restrict__ tbf) {
  __shared__ bf16x8 lds_a[16 * 64];   // 16 KB
  __shared__ bf16x8 lds_b[16 * 64];   // 16 KB

  int rtile = blockIdx.x;
  int ctile = blockIdx.y;
  int tid = threadIdx.x;
  int wave = tid >> 6;
  int lane = tid & 63;
  int q = lane >> 4;
  int l15 = lane & 15;
  int wr = wave >> 1;      // row half (0/1)
  int wc = wave & 1;       // col half (0/1)
  int rowTile = rtile * 128;
  int colTile = ctile * 128;

  // Per-lane global source pointers for the 4 A-chunks and 4 B-chunks this
  // wave stages each K-iter. Chunk id c = wave*4 + t; grp16 = c>>1, ks = c&1.
  const unsigned short* gA[4];
  const unsigned short* gB[4];
  #pragma unroll
  for (int t = 0; t < 4; t++) {
    int c = wave * 4 + t;
    int g16 = c >> 1, ks = c & 1;
    gA[t] = nx + (size_t)(rowTile + g16 * 16 + l15) * E_DIM + ks * 32 + q * 8;
    int cls = colTile + g16 * 16 + l15;
    if (cls >= C_CLS) cls = C_CLS - 1;          // clamp; masked in epilogue
    gB[t] = nw + (size_t)cls * E_DIM + ks * 32 + q * 8;
  }

  // Stage tile 0.
  #pragma unroll
  for (int t = 0; t < 4; t++) {
    int c = wave * 4 + t;
    __builtin_amdgcn_global_load_lds(
        (const __attribute__((address_space(1))) void*)(gA[t]),
        (__attribute__((address_space(3))) void*)(&lds_a[c * 64]), 16, 0, 0);
    __builtin_amdgcn_global_load_lds(
        (const __attribute__((address_space(1))) void*)(gB[t]),
        (__attribute__((address_space(3))) void*)(&lds_b[c * 64]), 16, 0, 0);
  }

  f32x4 acc[4][4] = {};

  #pragma unroll
  for (int kt = 0; kt < 8; kt++) {
    __syncthreads();   // staging of tile kt visible to all waves
    bf16x8 afr[2][4], bfr[2][4];
    #pragma unroll
    for (int ks = 0; ks < 2; ks++) {
      #pragma unroll
      for (int i = 0; i < 4; i++)
        afr[ks][i] = lds_a[((wr * 4 + i) * 2 + ks) * 64 + lane];
      #pragma unroll
      for (int j = 0; j < 4; j++)
        bfr[ks][j] = lds_b[((wc * 4 + j) * 2 + ks) * 64 + lane];
    }
    __syncthreads();   // all fragment reads done -> LDS reusable
    if (kt < 7) {
      #pragma unroll
      for (int t = 0; t < 4; t++) {
        int c = wave * 4 + t;
        __builtin_amdgcn_global_load_lds(
            (const __attribute__((address_space(1))) void*)(gA[t] + (kt + 1) * 64),
            (__attribute__((address_space(3))) void*)(&lds_a[c * 64]), 16, 0, 0);
        __builtin_amdgcn_global_load_lds(
            (const __attribute__((address_space(1))) void*)(gB[t] + (kt + 1) * 64),
            (__attribute__((address_space(3))) void*)(&lds_b[c * 64]), 16, 0, 0);
      }
    }
    #pragma unroll
    for (int ks = 0; ks < 2; ks++)
      #pragma unroll
      for (int i = 0; i < 4; i++)
        #pragma unroll
        for (int j = 0; j < 4; j++)
          acc[i][j] = __builtin_amdgcn_mfma_f32_16x16x32_bf16(afr[ks][i], bfr[ks][j],
                                                              acc[i][j], 0, 0, 0);
  }

  // Epilogue. C/D layout: within a 16x16 tile, row = 4*q + reg, col = l15.
  // Wave covers rows [rowTile + wr*64, +64), cols [colTile + wc*64, +64).
  int colW = colTile + wc * 64;
  #pragma unroll
  for (int msub = 0; msub < 4; msub++) {
    #pragma unroll
    for (int reg = 0; reg < 4; reg++) {
      int grow = rowTile + wr * 64 + msub * 16 + 4 * q + reg;
      int lab = label[grow];
      float v[4];
      float vmax = -INFINITY;
      #pragma unroll
      for (int ns = 0; ns < 4; ns++) {
        int col = colW + ns * 16 + l15;
        v[ns] = acc[msub][ns][reg];
        if (col < C_CLS) {
          vmax = fmaxf(vmax, v[ns]);
          if (col == lab) tbf[grow] = v[ns];   // bf16-GEMM cos at label position
        }
      }
      #pragma unroll
      for (int m = 1; m < 16; m <<= 1) vmax = fmaxf(vmax, __shfl_xor(vmax, m, 64));
      float sum = 0.f;
      #pragma unroll
      for (int ns = 0; ns < 4; ns++) {
        int col = colW + ns * 16 + l15;
        if (col < C_CLS) sum += __expf(v[ns] - vmax);
      }
      #pragma unroll
      for (int m = 1; m < 16; m <<= 1) sum += __shfl_xor(sum, m, 64);
      if (l15 == 0) {
        size_t p = (size_t)grow * NCT2 + (size_t)ctile * 2 + wc;
        pm[p] = vmax;
        pl[p] = sum;
      }
    }
  }
}

// Combine per-tile partials -> row logsumexp, swap in margin logit, mean-reduce.
__global__ __launch_bounds__(256) void k_reduce(const float* __restrict__ pm,
                                                const float* __restrict__ pl,
                                                const float* __restrict__ t,
                                                const float* __restrict__ tbf,
                                                float* __restrict__ out) {
  int row = blockIdx.x;
  int tid = threadIdx.x;
  float m = -INFINITY, l = 0.f;
  for (int j = tid; j < NCT2; j += 256) {
    float mj = pm[(size_t)row * NCT2 + j];
    float lj = pl[(size_t)row * NCT2 + j];
    if (mj > m) { l = l * __expf(m - mj) + lj; m = mj; }
    else        { l += lj * __expf(mj - m); }
  }
  __shared__ float sm[256], sl[256];
  sm[tid] = m; sl[tid] = l;
  __syncthreads();
  for (int s = 128; s > 0; s >>= 1) {
    if (tid < s) {
      float m1 = sm[tid], l1 = sl[tid];
      float m2 = sm[tid + s], l2 = sl[tid + s];
      float M = fmaxf(m1, m2);
      float L;
      if (M == -INFINITY) L = 0.f;
      else L = l1 * __expf(m1 - M) + l2 * __expf(m2 - M);
      sm[tid] = M; sl[tid] = L;
    }
    __syncthreads();
  }
  if (tid == 0) {
    float M0 = sm[0], L0 = sl[0];
    float tv = t[row];
    float tb = tbf[row];
    float sint = sqrtf(fmaxf(0.f, 1.f - tv * tv));
    float cosm = tv * COS_M - sint * SIN_M;
    float M = fmaxf(M0, cosm);
    float L = L0 * expf(M0 - M) - expf(tb - M) + expf(cosm - M);
    float loss = logf(L) + M - cosm;
    atomicAdd(out, loss * (1.0f / N_ROWS));
  }
}

extern "C" void kernel_launch(void* const* d_in, const int* in_sizes, int n_in,
                              void* d_out, int out_size, void* d_ws, size_t ws_size,
                              hipStream_t stream) {
  const float* x = (const float*)d_in[0];
  const int* label = (const int*)d_in[1];
  const float* w = (const float*)d_in[2];
  float* out = (float*)d_out;
  char* ws = (char*)d_ws;

  size_t off = 0;
  unsigned short* nx = (unsigned short*)(ws + off); off += (size_t)N_ROWS * E_DIM * 2;   // 4 MB
  unsigned short* nw = (unsigned short*)(ws + off); off += (size_t)C_CLS * E_DIM * 2;    // 51.5 MB
  float* xn  = (float*)(ws + off); off += (size_t)N_ROWS * 4;
  float* wn  = (float*)(ws + off); off += (size_t)50304 * 4;
  float* tv  = (float*)(ws + off); off += (size_t)N_ROWS * 4;
  float* tbf = (float*)(ws + off); off += (size_t)N_ROWS * 4;
  float* pm  = (float*)(ws + off); off += (size_t)N_ROWS * NCT2 * 4;                     // 12.9 MB
  float* pl  = (float*)(ws + off); off += (size_t)N_ROWS * NCT2 * 4;                     // 12.9 MB

  hipMemsetAsync(d_out, 0, sizeof(float), stream);
  k_norm<<<N_ROWS, 256, 0, stream>>>(x, nx, xn);
  k_norm<<<C_CLS, 256, 0, stream>>>(w, nw, wn);
  k_target<<<N_ROWS, 256, 0, stream>>>(x, w, label, xn, wn, tv);
  dim3 g(N_ROWS / 128, NTILE);
  k_gemm<<<g, 256, 0, stream>>>(nx, nw, label, pm, pl, tbf);
  k_reduce<<<N_ROWS, 256, 0, stream>>>(pm, pl, tv, tbf, out);
}